// Round 1
// baseline (345.996 us; speedup 1.0000x reference)
//
#include <hip/hip_runtime.h>

#define NN 100000
#define NE 3200000
#define NQ (NE / 4)

// Zero both accumulators (agg1 in ws, agg2 in d_out). Deterministic each call.
__global__ void zero2_kernel(float* __restrict__ a, float* __restrict__ b, int n) {
    int i = blockIdx.x * blockDim.x + threadIdx.x;
    int stride = gridDim.x * blockDim.x;
    for (; i < n; i += stride) { a[i] = 0.0f; b[i] = 0.0f; }
}

// Scalar scatter-add over edges: agg[dst[e]] += h[src[e]], 4 edges/thread.
__global__ __launch_bounds__(256) void edge_scatter_kernel(
        const float* __restrict__ h,
        const int4* __restrict__ src4,
        const int4* __restrict__ dst4,
        float* __restrict__ agg, int nquad) {
    int i = blockIdx.x * blockDim.x + threadIdx.x;
    if (i >= nquad) return;
    int4 s = src4[i];
    int4 d = dst4[i];
    float fx = h[s.x];
    float fy = h[s.y];
    float fz = h[s.z];
    float fw = h[s.w];
    atomicAdd(&agg[d.x], fx);
    atomicAdd(&agg[d.y], fy);
    atomicAdd(&agg[d.z], fz);
    atomicAdd(&agg[d.w], fw);
}

// Per-node: s[m] = sum_j relu(agg1[m]*W1[j] + b1[j]) * W2[j]
__global__ __launch_bounds__(256) void node_mlp_kernel(
        const float* __restrict__ agg1,
        const float* __restrict__ W1,
        const float* __restrict__ b1,
        const float* __restrict__ W2,
        float* __restrict__ s, int n) {
    int i = blockIdx.x * blockDim.x + threadIdx.x;
    if (i >= n) return;
    float a = agg1[i];
    float acc = 0.0f;
#pragma unroll
    for (int j = 0; j < 16; ++j) {
        float h = fmaxf(fmaf(a, W1[j], b1[j]), 0.0f);
        acc = fmaf(h, W2[j], acc);
    }
    s[i] = acc;
}

// out[n] = relu(out[n] + b2)  (out currently holds agg2)
__global__ __launch_bounds__(256) void finalize_kernel(
        float* __restrict__ out, const float* __restrict__ b2, int n) {
    int i = blockIdx.x * blockDim.x + threadIdx.x;
    if (i >= n) return;
    out[i] = fmaxf(out[i] + b2[0], 0.0f);
}

extern "C" void kernel_launch(void* const* d_in, const int* in_sizes, int n_in,
                              void* d_out, int out_size, void* d_ws, size_t ws_size,
                              hipStream_t stream) {
    const float* features = (const float*)d_in[0];
    const int*   src      = (const int*)d_in[1];
    const int*   dst      = (const int*)d_in[2];
    const float* W1       = (const float*)d_in[3];
    const float* b1       = (const float*)d_in[4];
    const float* W2       = (const float*)d_in[5];
    const float* b2       = (const float*)d_in[6];
    float* out = (float*)d_out;

    float* agg1 = (float*)d_ws;          // NN floats
    float* sbuf = agg1 + NN;             // NN floats

    const int4* src4 = (const int4*)src;
    const int4* dst4 = (const int4*)dst;

    // 1. zero agg1 and agg2(=d_out)
    zero2_kernel<<<256, 256, 0, stream>>>(agg1, out, NN);

    // 2. layer-1 edge aggregation
    int eb = (NQ + 255) / 256;
    edge_scatter_kernel<<<eb, 256, 0, stream>>>(features, src4, dst4, agg1, NQ);

    // 3. collapse node MLP: s = (relu(agg1*W1+b1)) @ W2
    int nb = (NN + 255) / 256;
    node_mlp_kernel<<<nb, 256, 0, stream>>>(agg1, W1, b1, W2, sbuf, NN);

    // 4. layer-2 edge aggregation directly into d_out
    edge_scatter_kernel<<<eb, 256, 0, stream>>>(sbuf, src4, dst4, out, NQ);

    // 5. final bias + relu
    finalize_kernel<<<nb, 256, 0, stream>>>(out, b2, NN);
}

// Round 2
// 329.127 us; speedup vs baseline: 1.0513x; 1.0513x over previous
//
#include <hip/hip_runtime.h>

#define NN 100000
#define NE 3200000
#define NQ (NE / 4)
#define NREP 8

// Physical XCD id of the CU this wave runs on (0..7 on MI355X).
__device__ __forceinline__ int xcc_id() {
    int x;
    asm volatile("s_getreg_b32 %0, hwreg(HW_REG_XCC_ID)" : "=s"(x));
    return x & 7;
}

__global__ void zero_kernel(float* __restrict__ p, int n) {
    int i = blockIdx.x * blockDim.x + threadIdx.x;
    int st = gridDim.x * blockDim.x;
    for (; i < n; i += st) p[i] = 0.0f;
}

// Scatter-add into the replica owned by this workgroup's XCD.
// Workgroup-scope relaxed atomics stay in the local L2 (no write-through):
// only blocks on this XCD touch this replica, and they all share that L2.
__global__ __launch_bounds__(256) void edge_scatter_rep_kernel(
        const float* __restrict__ h,
        const int4* __restrict__ src4,
        const int4* __restrict__ dst4,
        float* __restrict__ rep, int nquad) {
    int i = blockIdx.x * blockDim.x + threadIdx.x;
    if (i >= nquad) return;
    float* r = rep + (size_t)xcc_id() * NN;
    int4 s = src4[i];
    int4 d = dst4[i];
    float fx = h[s.x];
    float fy = h[s.y];
    float fz = h[s.z];
    float fw = h[s.w];
    __hip_atomic_fetch_add(&r[d.x], fx, __ATOMIC_RELAXED, __HIP_MEMORY_SCOPE_WORKGROUP);
    __hip_atomic_fetch_add(&r[d.y], fy, __ATOMIC_RELAXED, __HIP_MEMORY_SCOPE_WORKGROUP);
    __hip_atomic_fetch_add(&r[d.z], fz, __ATOMIC_RELAXED, __HIP_MEMORY_SCOPE_WORKGROUP);
    __hip_atomic_fetch_add(&r[d.w], fw, __ATOMIC_RELAXED, __HIP_MEMORY_SCOPE_WORKGROUP);
}

// agg1[i] = sum over 8 replicas; re-zero replicas for pass 2;
// s[i] = sum_j relu(agg1*W1[j]+b1[j]) * W2[j]
__global__ __launch_bounds__(256) void reduce_mlp_kernel(
        float* __restrict__ rep,
        const float* __restrict__ W1,
        const float* __restrict__ b1,
        const float* __restrict__ W2,
        float* __restrict__ s, int n) {
    int i = blockIdx.x * blockDim.x + threadIdx.x;
    if (i >= n) return;
    float a = 0.0f;
#pragma unroll
    for (int r = 0; r < NREP; ++r) {
        a += rep[r * NN + i];
        rep[r * NN + i] = 0.0f;
    }
    float acc = 0.0f;
#pragma unroll
    for (int j = 0; j < 16; ++j) {
        float hh = fmaxf(fmaf(a, W1[j], b1[j]), 0.0f);
        acc = fmaf(hh, W2[j], acc);
    }
    s[i] = acc;
}

// out[i] = relu(sum over replicas + b2)
__global__ __launch_bounds__(256) void final_kernel(
        const float* __restrict__ rep,
        const float* __restrict__ b2,
        float* __restrict__ out, int n) {
    int i = blockIdx.x * blockDim.x + threadIdx.x;
    if (i >= n) return;
    float a = 0.0f;
#pragma unroll
    for (int r = 0; r < NREP; ++r) a += rep[r * NN + i];
    out[i] = fmaxf(a + b2[0], 0.0f);
}

// ---------- fallback path (small ws): round-1 device-scope version ----------
__global__ void zero2_kernel(float* __restrict__ a, float* __restrict__ b, int n) {
    int i = blockIdx.x * blockDim.x + threadIdx.x;
    int st = gridDim.x * blockDim.x;
    for (; i < n; i += st) { a[i] = 0.0f; b[i] = 0.0f; }
}
__global__ __launch_bounds__(256) void edge_scatter_kernel(
        const float* __restrict__ h, const int4* __restrict__ src4,
        const int4* __restrict__ dst4, float* __restrict__ agg, int nquad) {
    int i = blockIdx.x * blockDim.x + threadIdx.x;
    if (i >= nquad) return;
    int4 s = src4[i]; int4 d = dst4[i];
    atomicAdd(&agg[d.x], h[s.x]);
    atomicAdd(&agg[d.y], h[s.y]);
    atomicAdd(&agg[d.z], h[s.z]);
    atomicAdd(&agg[d.w], h[s.w]);
}
__global__ __launch_bounds__(256) void finalize_kernel(
        float* __restrict__ out, const float* __restrict__ b2, int n) {
    int i = blockIdx.x * blockDim.x + threadIdx.x;
    if (i >= n) return;
    out[i] = fmaxf(out[i] + b2[0], 0.0f);
}

extern "C" void kernel_launch(void* const* d_in, const int* in_sizes, int n_in,
                              void* d_out, int out_size, void* d_ws, size_t ws_size,
                              hipStream_t stream) {
    const float* features = (const float*)d_in[0];
    const int*   src      = (const int*)d_in[1];
    const int*   dst      = (const int*)d_in[2];
    const float* W1       = (const float*)d_in[3];
    const float* b1       = (const float*)d_in[4];
    const float* W2       = (const float*)d_in[5];
    const float* b2       = (const float*)d_in[6];
    float* out = (float*)d_out;

    const int4* src4 = (const int4*)src;
    const int4* dst4 = (const int4*)dst;

    const int eb = (NQ + 255) / 256;
    const int nb = (NN + 255) / 256;

    const size_t need = (size_t)(NREP * NN + NN) * sizeof(float);
    if (ws_size >= need) {
        float* rep  = (float*)d_ws;            // NREP*NN floats
        float* sbuf = rep + NREP * NN;         // NN floats

        zero_kernel<<<512, 256, 0, stream>>>(rep, NREP * NN);
        edge_scatter_rep_kernel<<<eb, 256, 0, stream>>>(features, src4, dst4, rep, NQ);
        reduce_mlp_kernel<<<nb, 256, 0, stream>>>(rep, W1, b1, W2, sbuf, NN);
        edge_scatter_rep_kernel<<<eb, 256, 0, stream>>>(sbuf, src4, dst4, rep, NQ);
        final_kernel<<<nb, 256, 0, stream>>>(rep, b2, out, NN);
    } else {
        float* agg1 = (float*)d_ws;
        float* sbuf = agg1 + NN;
        zero2_kernel<<<256, 256, 0, stream>>>(agg1, out, NN);
        edge_scatter_kernel<<<eb, 256, 0, stream>>>(features, src4, dst4, agg1, NQ);
        reduce_mlp_kernel<<<nb, 256, 0, stream>>>(agg1, W1, b1, W2, sbuf, NN); // NREP loop reads past agg1 in this path
        edge_scatter_kernel<<<eb, 256, 0, stream>>>(sbuf, src4, dst4, out, NQ);
        finalize_kernel<<<nb, 256, 0, stream>>>(out, b2, NN);
    }
}

// Round 3
// 81.165 us; speedup vs baseline: 4.2629x; 4.0550x over previous
//
#include <hip/hip_runtime.h>

#define NN 100000
#define NE 3200000
#define NQ (NE / 4)

// ---------------- Plan A/B: chunked-LDS scatter, no global atomics ----------

// One block = (edge-slice s, node-chunk c). Accumulate h[src] into LDS for
// dst in chunk c, then write the whole chunk to a private partial slot.
template <int CB>
__global__ __launch_bounds__(1024) void scatter_lds_kernel(
        const float* __restrict__ h,
        const int4* __restrict__ src4,
        const int4* __restrict__ dst4,
        float* __restrict__ partial,   // [C][S][1<<CB]
        int nslices) {
    __shared__ float acc[1 << CB];
    const int cmask = (1 << CB) - 1;
    const int s = blockIdx.x, c = blockIdx.y;
    for (int i = threadIdx.x; i < (1 << CB); i += blockDim.x) acc[i] = 0.0f;
    __syncthreads();
    const int q0 = (int)(((long long)NQ * s) / nslices);
    const int q1 = (int)(((long long)NQ * (s + 1)) / nslices);
    for (int q = q0 + threadIdx.x; q < q1; q += blockDim.x) {
        int4 d = dst4[q];
        int4 sv = src4[q];
        if ((d.x >> CB) == c) atomicAdd(&acc[d.x & cmask], h[sv.x]);
        if ((d.y >> CB) == c) atomicAdd(&acc[d.y & cmask], h[sv.y]);
        if ((d.z >> CB) == c) atomicAdd(&acc[d.z & cmask], h[sv.z]);
        if ((d.w >> CB) == c) atomicAdd(&acc[d.w & cmask], h[sv.w]);
    }
    __syncthreads();
    float* out = partial + (((size_t)c * nslices + s) << CB);
    for (int i = threadIdx.x; i < (1 << CB); i += blockDim.x) out[i] = acc[i];
}

// agg1[n] = sum over slice-partials; s[n] = sum_j relu(agg1*W1[j]+b1[j])*W2[j]
template <int CB>
__global__ __launch_bounds__(256) void reduce_mlp_kernel(
        const float* __restrict__ partial, int nslices,
        const float* __restrict__ W1, const float* __restrict__ b1,
        const float* __restrict__ W2,
        float* __restrict__ sout, int n) {
    int i = blockIdx.x * blockDim.x + threadIdx.x;
    if (i >= n) return;
    const int c = i >> CB, idx = i & ((1 << CB) - 1);
    const float* base = partial + (((size_t)c * nslices) << CB) + idx;
    float a = 0.0f;
#pragma unroll 8
    for (int s = 0; s < nslices; ++s) a += base[(size_t)s << CB];
    float r = 0.0f;
#pragma unroll
    for (int j = 0; j < 16; ++j)
        r = fmaf(fmaxf(fmaf(a, W1[j], b1[j]), 0.0f), W2[j], r);
    sout[i] = r;
}

template <int CB>
__global__ __launch_bounds__(256) void reduce_final_kernel(
        const float* __restrict__ partial, int nslices,
        const float* __restrict__ b2,
        float* __restrict__ out, int n) {
    int i = blockIdx.x * blockDim.x + threadIdx.x;
    if (i >= n) return;
    const int c = i >> CB, idx = i & ((1 << CB) - 1);
    const float* base = partial + (((size_t)c * nslices) << CB) + idx;
    float a = 0.0f;
#pragma unroll 8
    for (int s = 0; s < nslices; ++s) a += base[(size_t)s << CB];
    out[i] = fmaxf(a + b2[0], 0.0f);
}

// ---------------- Fallback: R2 global-atomic path ---------------------------
__global__ void zero_kernel(float* __restrict__ p, int n) {
    int i = blockIdx.x * blockDim.x + threadIdx.x;
    int st = gridDim.x * blockDim.x;
    for (; i < n; i += st) p[i] = 0.0f;
}
__global__ __launch_bounds__(256) void edge_scatter_kernel(
        const float* __restrict__ h, const int4* __restrict__ src4,
        const int4* __restrict__ dst4, float* __restrict__ agg, int nquad) {
    int i = blockIdx.x * blockDim.x + threadIdx.x;
    if (i >= nquad) return;
    int4 s = src4[i]; int4 d = dst4[i];
    atomicAdd(&agg[d.x], h[s.x]);
    atomicAdd(&agg[d.y], h[s.y]);
    atomicAdd(&agg[d.z], h[s.z]);
    atomicAdd(&agg[d.w], h[s.w]);
}
__global__ __launch_bounds__(256) void mlp_kernel(
        const float* __restrict__ agg1, const float* __restrict__ W1,
        const float* __restrict__ b1, const float* __restrict__ W2,
        float* __restrict__ sout, int n) {
    int i = blockIdx.x * blockDim.x + threadIdx.x;
    if (i >= n) return;
    float a = agg1[i], r = 0.0f;
#pragma unroll
    for (int j = 0; j < 16; ++j)
        r = fmaf(fmaxf(fmaf(a, W1[j], b1[j]), 0.0f), W2[j], r);
    sout[i] = r;
}
__global__ __launch_bounds__(256) void finalize_kernel(
        float* __restrict__ out, const float* __restrict__ b2, int n) {
    int i = blockIdx.x * blockDim.x + threadIdx.x;
    if (i >= n) return;
    out[i] = fmaxf(out[i] + b2[0], 0.0f);
}

extern "C" void kernel_launch(void* const* d_in, const int* in_sizes, int n_in,
                              void* d_out, int out_size, void* d_ws, size_t ws_size,
                              hipStream_t stream) {
    const float* features = (const float*)d_in[0];
    const int*   src      = (const int*)d_in[1];
    const int*   dst      = (const int*)d_in[2];
    const float* W1       = (const float*)d_in[3];
    const float* b1       = (const float*)d_in[4];
    const float* W2       = (const float*)d_in[5];
    const float* b2       = (const float*)d_in[6];
    float* out = (float*)d_out;

    const int4* src4 = (const int4*)src;
    const int4* dst4 = (const int4*)dst;
    const int nb = (NN + 255) / 256;

    // Plan A: CB=15 (128 KB LDS), C=4 chunks, S=64 slices -> 256 blocks.
    {
        const int S = 64, C = 4;
        const size_t psz = ((size_t)C * S) << 15;           // 8.4M floats
        const size_t need = (psz + NN) * sizeof(float);     // ~34 MB
        if (ws_size >= need) {
            float* partial = (float*)d_ws;
            float* sbuf = partial + psz;
            dim3 g(S, C);
            scatter_lds_kernel<15><<<g, 1024, 0, stream>>>(features, src4, dst4, partial, S);
            reduce_mlp_kernel<15><<<nb, 256, 0, stream>>>(partial, S, W1, b1, W2, sbuf, NN);
            scatter_lds_kernel<15><<<g, 1024, 0, stream>>>(sbuf, src4, dst4, partial, S);
            reduce_final_kernel<15><<<nb, 256, 0, stream>>>(partial, S, b2, out, NN);
            return;
        }
    }
    // Plan B: CB=14 (64 KB LDS), C=7 chunks, S=36 slices -> 252 blocks.
    {
        const int S = 36, C = 7;
        const size_t psz = ((size_t)C * S) << 14;
        const size_t need = (psz + NN) * sizeof(float);     // ~17 MB
        if (ws_size >= need) {
            float* partial = (float*)d_ws;
            float* sbuf = partial + psz;
            dim3 g(S, C);
            scatter_lds_kernel<14><<<g, 1024, 0, stream>>>(features, src4, dst4, partial, S);
            reduce_mlp_kernel<14><<<nb, 256, 0, stream>>>(partial, S, W1, b1, W2, sbuf, NN);
            scatter_lds_kernel<14><<<g, 1024, 0, stream>>>(sbuf, src4, dst4, partial, S);
            reduce_final_kernel<14><<<nb, 256, 0, stream>>>(partial, S, b2, out, NN);
            return;
        }
    }
    // Fallback: global-atomic path (needs 2*NN floats).
    {
        float* agg1 = (float*)d_ws;
        float* sbuf = agg1 + NN;
        const int eb = (NQ + 255) / 256;
        zero_kernel<<<256, 256, 0, stream>>>(agg1, NN);
        edge_scatter_kernel<<<eb, 256, 0, stream>>>(features, src4, dst4, agg1, NQ);
        mlp_kernel<<<nb, 256, 0, stream>>>(agg1, W1, b1, W2, sbuf, NN);
        zero_kernel<<<256, 256, 0, stream>>>(out, NN);
        edge_scatter_kernel<<<eb, 256, 0, stream>>>(sbuf, src4, dst4, out, NQ);
        finalize_kernel<<<nb, 256, 0, stream>>>(out, b2, NN);
    }
}